// Round 1
// baseline (65.204 us; speedup 1.0000x reference)
//
#include <hip/hip_runtime.h>
#include <hip/hip_bf16.h>

typedef __attribute__((ext_vector_type(8))) short bf16x8;
typedef __attribute__((ext_vector_type(4))) float f32x4;

#define T_DIM 32
#define B_DIM 8192
#define S_DIM 256
#define H_DIM 128
#define BM    64          // batch rows per block
#define NCHUNK (B_DIM / BM)   // 128 chunks per t

__device__ __forceinline__ uint32_t cvt_pk_bf16(float lo, float hi) {
  uint32_t r;
  asm("v_cvt_pk_bf16_f32 %0, %1, %2" : "=v"(r) : "v"(lo), "v"(hi));
  return r;
}

__global__ __launch_bounds__(256, 2) void cvar_mlp_kernel(
    const float* __restrict__ states, const float* __restrict__ W1,
    const float* __restrict__ b1, const float* __restrict__ W2,
    const float* __restrict__ b2, float* __restrict__ out)
{
  // 64 rows x 256 k as bf16, row stride 512 B, XOR-swizzled
  __shared__ __align__(16) char lds[BM * 512];
  __shared__ float red[4][BM];

  const int tid  = threadIdx.x;
  const int wid  = tid >> 6;
  const int lane = tid & 63;
  const int l15  = lane & 15;
  const int lg   = lane >> 4;          // 0..3

  // XCD-grouped mapping: blocks with same (bidx&7) share t -> W1[t] lives in one XCD L2
  const int bidx   = blockIdx.x;       // 0..4095
  const int xcd    = bidx & 7;
  const int slot   = bidx >> 3;        // 0..511
  const int t      = xcd * 4 + (slot >> 7);
  const int bchunk = slot & 127;
  const int b0     = bchunk * BM;

  const float*  Ag  = states + ((size_t)t * B_DIM + b0) * S_DIM;  // contiguous 64x256 slab
  const float*  W1g = W1 + (size_t)t * (S_DIM * H_DIM);
  const float4* A4  = reinterpret_cast<const float4*>(Ag);

  // ---- 1) issue states loads (HBM, longest latency) ----
  float4 av[16];
#pragma unroll
  for (int i = 0; i < 16; ++i)
    av[i] = A4[i * 256 + tid];

  // ---- 2) W1 fragment preload into registers (L2) ----
  // B-operand frag for mfma_f32_16x16x32_bf16: lane holds col n = lane&15,
  // k = ks*32 + (lane>>4)*8 + j, j=0..7
  bf16x8 bfr[2][8];
#pragma unroll
  for (int nloc = 0; nloc < 2; ++nloc) {
    const int ncol = (wid * 2 + nloc) * 16 + l15;
#pragma unroll
    for (int ks = 0; ks < 8; ++ks) {
      const int kbase = ks * 32 + lg * 8;
      float e[8];
#pragma unroll
      for (int j = 0; j < 8; ++j)
        e[j] = W1g[(size_t)(kbase + j) * H_DIM + ncol];
      union { uint32_t u[4]; bf16x8 v; } uu;
      uu.u[0] = cvt_pk_bf16(e[0], e[1]);
      uu.u[1] = cvt_pk_bf16(e[2], e[3]);
      uu.u[2] = cvt_pk_bf16(e[4], e[5]);
      uu.u[3] = cvt_pk_bf16(e[6], e[7]);
      bfr[nloc][ks] = uu.v;
    }
  }

  // ---- 3) states f32 -> bf16 -> LDS (swizzled) ----
#pragma unroll
  for (int i = 0; i < 16; ++i) {
    const int f   = i * 256 + tid;     // float4 index within 64x256 tile
    const int row = f >> 6;
    const int kq  = f & 63;            // k = kq*4
    const uint32_t lo = cvt_pk_bf16(av[i].x, av[i].y);
    const uint32_t hi = cvt_pk_bf16(av[i].z, av[i].w);
    int byteoff = row * 512 + kq * 8;
    byteoff ^= (row & 7) << 4;         // bank-conflict swizzle
    *reinterpret_cast<uint2*>(&lds[byteoff]) = make_uint2(lo, hi);
  }
  __syncthreads();

  // ---- 4) MFMA: h-tile = states_tile @ W1  (each wave: all 64 rows x its 32 cols) ----
  f32x4 acc[4][2];
#pragma unroll
  for (int mt = 0; mt < 4; ++mt)
#pragma unroll
    for (int nloc = 0; nloc < 2; ++nloc)
      acc[mt][nloc] = (f32x4){0.f, 0.f, 0.f, 0.f};

#pragma unroll
  for (int mt = 0; mt < 4; ++mt) {
    const int row = mt * 16 + l15;
    bf16x8 afr[8];
#pragma unroll
    for (int ks = 0; ks < 8; ++ks) {
      int byteoff = row * 512 + ks * 64 + lg * 16;
      byteoff ^= (row & 7) << 4;
      afr[ks] = *reinterpret_cast<const bf16x8*>(&lds[byteoff]);
    }
#pragma unroll
    for (int ks = 0; ks < 8; ++ks) {
      acc[mt][0] = __builtin_amdgcn_mfma_f32_16x16x32_bf16(afr[ks], bfr[0][ks], acc[mt][0], 0, 0, 0);
      acc[mt][1] = __builtin_amdgcn_mfma_f32_16x16x32_bf16(afr[ks], bfr[1][ks], acc[mt][1], 0, 0, 0);
    }
  }

  // ---- 5) fused epilogue: +b1, SiLU, *W2, row-reduce ----
  float b1c[2], w2c[2];
#pragma unroll
  for (int nloc = 0; nloc < 2; ++nloc) {
    const int col = (wid * 2 + nloc) * 16 + l15;
    b1c[nloc] = b1[(size_t)t * H_DIM + col];
    w2c[nloc] = W2[(size_t)t * H_DIM + col];
  }

#pragma unroll
  for (int mt = 0; mt < 4; ++mt) {
    float part[4];
#pragma unroll
    for (int r = 0; r < 4; ++r) {
      float s = 0.f;
#pragma unroll
      for (int nloc = 0; nloc < 2; ++nloc) {
        const float h   = acc[mt][nloc][r] + b1c[nloc];
        const float sig = 1.f / (1.f + __expf(-h));
        s += h * sig * w2c[nloc];
      }
      // sum over the 16 lanes holding this row's 16 columns (lane bits 0..3)
      s += __shfl_xor(s, 1);
      s += __shfl_xor(s, 2);
      s += __shfl_xor(s, 4);
      s += __shfl_xor(s, 8);
      part[r] = s;
    }
    if (l15 == 0) {
#pragma unroll
      for (int r = 0; r < 4; ++r)
        red[wid][mt * 16 + lg * 4 + r] = part[r];
    }
  }
  __syncthreads();

  // ---- 6) cross-wave reduce + b2, write out[t][b] ----
  if (tid < BM) {
    const float o = red[0][tid] + red[1][tid] + red[2][tid] + red[3][tid] + b2[t];
    out[(size_t)t * B_DIM + b0 + tid] = o;
  }
}

extern "C" void kernel_launch(void* const* d_in, const int* in_sizes, int n_in,
                              void* d_out, int out_size, void* d_ws, size_t ws_size,
                              hipStream_t stream) {
  const float* states = (const float*)d_in[0];
  const float* W1     = (const float*)d_in[1];
  const float* b1     = (const float*)d_in[2];
  const float* W2     = (const float*)d_in[3];
  const float* b2     = (const float*)d_in[4];
  float* out          = (float*)d_out;

  const int grid = T_DIM * NCHUNK;   // 4096
  cvar_mlp_kernel<<<grid, 256, 0, stream>>>(states, W1, b1, W2, b2, out);
}

// Round 2
// 58.644 us; speedup vs baseline: 1.1119x; 1.1119x over previous
//
#include <hip/hip_runtime.h>
#include <hip/hip_bf16.h>

typedef __attribute__((ext_vector_type(8))) short bf16x8;
typedef __attribute__((ext_vector_type(4))) float f32x4;

#define T_DIM 32
#define B_DIM 8192
#define S_DIM 256
#define H_DIM 128
#define BM    64              // batch rows per chunk
#define NCH   4               // chunks per block
#define BLOCKS_PER_T 32       // 8192 / (64*4)
// grid = 32 t * 32 = 1024 blocks

__device__ __forceinline__ uint32_t cvt_pk_bf16(float lo, float hi) {
  uint32_t r;
  asm("v_cvt_pk_bf16_f32 %0, %1, %2" : "=v"(r) : "v"(lo), "v"(hi));
  return r;
}

__global__ __launch_bounds__(256, 2) void cvar_mlp_kernel(
    const float* __restrict__ states, const float* __restrict__ W1,
    const float* __restrict__ b1, const float* __restrict__ W2,
    const float* __restrict__ b2, float* __restrict__ out)
{
  // double-buffered 64x256 bf16 states tile, row stride 512B, XOR-swizzled
  __shared__ __align__(16) char lds[2][BM * 512];
  __shared__ float red[2][4][BM];

  const int tid  = threadIdx.x;
  const int wid  = tid >> 6;
  const int lane = tid & 63;
  const int l15  = lane & 15;
  const int lg   = lane >> 4;          // 0..3

  // XCD-grouped: blocks with same (bidx&7) share a t-range -> W1[t] L2-local
  const int bidx = blockIdx.x;         // 0..1023
  const int xcd  = bidx & 7;
  const int slot = bidx >> 3;          // 0..127
  const int t    = xcd * 4 + (slot >> 5);
  const int cg   = slot & 31;
  const int b0   = cg * (BM * NCH);

  const float*  Ag  = states + ((size_t)t * B_DIM + b0) * S_DIM;
  const float4* A4  = reinterpret_cast<const float4*>(Ag);
  const float*  W1g = W1 + (size_t)t * (S_DIM * H_DIM);

  // ---- issue chunk-0 states loads (HBM, longest latency) ----
  float4 av[16];
#pragma unroll
  for (int i = 0; i < 16; ++i)
    av[i] = A4[i * 256 + tid];

  // ---- W1 fragment preload into registers (once per block, amortized 4x) ----
  // B-frag for mfma_f32_16x16x32_bf16: lane holds col n=lane&15, k=ks*32+lg*8+j
  bf16x8 bfr[2][8];
#pragma unroll
  for (int nloc = 0; nloc < 2; ++nloc) {
    const int ncol = (wid * 2 + nloc) * 16 + l15;
#pragma unroll
    for (int ks = 0; ks < 8; ++ks) {
      const int kbase = ks * 32 + lg * 8;
      float e[8];
#pragma unroll
      for (int j = 0; j < 8; ++j)
        e[j] = W1g[(size_t)(kbase + j) * H_DIM + ncol];
      union { uint32_t u[4]; bf16x8 v; } uu;
      uu.u[0] = cvt_pk_bf16(e[0], e[1]);
      uu.u[1] = cvt_pk_bf16(e[2], e[3]);
      uu.u[2] = cvt_pk_bf16(e[4], e[5]);
      uu.u[3] = cvt_pk_bf16(e[6], e[7]);
      bfr[nloc][ks] = uu.v;
    }
  }

  float b1c[2], w2c[2];
#pragma unroll
  for (int nloc = 0; nloc < 2; ++nloc) {
    const int col = (wid * 2 + nloc) * 16 + l15;
    b1c[nloc] = b1[(size_t)t * H_DIM + col];
    w2c[nloc] = W2[(size_t)t * H_DIM + col];
  }
  const float b2t = b2[t];
  float* outt = out + (size_t)t * B_DIM + b0;

  // ---- convert chunk 0 -> lds[0] ----
#pragma unroll
  for (int i = 0; i < 16; ++i) {
    const int f   = i * 256 + tid;
    const int row = f >> 6;
    const int kq  = f & 63;
    const uint32_t lo = cvt_pk_bf16(av[i].x, av[i].y);
    const uint32_t hi = cvt_pk_bf16(av[i].z, av[i].w);
    int byteoff = row * 512 + kq * 8;
    byteoff ^= (row & 7) << 4;
    *reinterpret_cast<uint2*>(&lds[0][byteoff]) = make_uint2(lo, hi);
  }
  __syncthreads();

  // ---- pipelined chunk loop ----
  for (int c = 0; c < NCH; ++c) {
    const int cur = c & 1;

    // prefetch next chunk's states into registers (in flight across MFMA)
    if (c + 1 < NCH) {
#pragma unroll
      for (int i = 0; i < 16; ++i)
        av[i] = A4[(c + 1) * (BM * S_DIM / 4) + i * 256 + tid];
    }

    // MFMA: 64 rows x this wave's 32 cols
    f32x4 acc[4][2];
#pragma unroll
    for (int mt = 0; mt < 4; ++mt)
#pragma unroll
      for (int nloc = 0; nloc < 2; ++nloc)
        acc[mt][nloc] = (f32x4){0.f, 0.f, 0.f, 0.f};

#pragma unroll
    for (int mt = 0; mt < 4; ++mt) {
      const int row = mt * 16 + l15;
      bf16x8 afr[8];
#pragma unroll
      for (int ks = 0; ks < 8; ++ks) {
        int byteoff = row * 512 + ks * 64 + lg * 16;
        byteoff ^= (row & 7) << 4;
        afr[ks] = *reinterpret_cast<const bf16x8*>(&lds[cur][byteoff]);
      }
#pragma unroll
      for (int ks = 0; ks < 8; ++ks) {
        acc[mt][0] = __builtin_amdgcn_mfma_f32_16x16x32_bf16(afr[ks], bfr[0][ks], acc[mt][0], 0, 0, 0);
        acc[mt][1] = __builtin_amdgcn_mfma_f32_16x16x32_bf16(afr[ks], bfr[1][ks], acc[mt][1], 0, 0, 0);
      }
    }

    // fused epilogue: +b1, SiLU, *W2, 16-lane row-reduce -> red[cur]
#pragma unroll
    for (int mt = 0; mt < 4; ++mt) {
      float part[4];
#pragma unroll
      for (int r = 0; r < 4; ++r) {
        float s = 0.f;
#pragma unroll
        for (int nloc = 0; nloc < 2; ++nloc) {
          const float h   = acc[mt][nloc][r] + b1c[nloc];
          const float sig = 1.f / (1.f + __expf(-h));
          s += h * sig * w2c[nloc];
        }
        s += __shfl_xor(s, 1);
        s += __shfl_xor(s, 2);
        s += __shfl_xor(s, 4);
        s += __shfl_xor(s, 8);
        part[r] = s;
      }
      if (l15 == 0) {
#pragma unroll
        for (int r = 0; r < 4; ++r)
          red[cur][wid][mt * 16 + lg * 4 + r] = part[r];
      }
    }

    // convert prefetched chunk -> other LDS buffer (prev reads done: barrier c-1)
    if (c + 1 < NCH) {
#pragma unroll
      for (int i = 0; i < 16; ++i) {
        const int f   = i * 256 + tid;
        const int row = f >> 6;
        const int kq  = f & 63;
        const uint32_t lo = cvt_pk_bf16(av[i].x, av[i].y);
        const uint32_t hi = cvt_pk_bf16(av[i].z, av[i].w);
        int byteoff = row * 512 + kq * 8;
        byteoff ^= (row & 7) << 4;
        *reinterpret_cast<uint2*>(&lds[cur ^ 1][byteoff]) = make_uint2(lo, hi);
      }
    }
    __syncthreads();

    // cross-wave reduce + b2, write out (red[cur] reused only at c+2: safe)
    if (tid < BM) {
      const float o = red[cur][0][tid] + red[cur][1][tid] +
                      red[cur][2][tid] + red[cur][3][tid] + b2t;
      outt[c * BM + tid] = o;
    }
  }
}

extern "C" void kernel_launch(void* const* d_in, const int* in_sizes, int n_in,
                              void* d_out, int out_size, void* d_ws, size_t ws_size,
                              hipStream_t stream) {
  const float* states = (const float*)d_in[0];
  const float* W1     = (const float*)d_in[1];
  const float* b1     = (const float*)d_in[2];
  const float* W2     = (const float*)d_in[3];
  const float* b2     = (const float*)d_in[4];
  float* out          = (float*)d_out;

  const int grid = T_DIM * BLOCKS_PER_T;   // 1024
  cvar_mlp_kernel<<<grid, 256, 0, stream>>>(states, W1, b1, W2, b2, out);
}

// Round 3
// 55.454 us; speedup vs baseline: 1.1758x; 1.0575x over previous
//
#include <hip/hip_runtime.h>
#include <hip/hip_bf16.h>

typedef __attribute__((ext_vector_type(8))) short bf16x8;
typedef __attribute__((ext_vector_type(4))) float f32x4;

#define T_DIM 32
#define B_DIM 8192
#define S_DIM 256
#define H_DIM 128
#define BM    64              // batch rows per chunk
#define NCH   8               // chunks per block
#define BLOCKS_PER_T 16       // 8192 / (64*8)
// grid = 32 t * 16 = 512 blocks = exactly 2 per CU -> no mid-kernel restarts

__device__ __forceinline__ uint32_t cvt_pk_bf16(float lo, float hi) {
  uint32_t r;
  asm("v_cvt_pk_bf16_f32 %0, %1, %2" : "=v"(r) : "v"(lo), "v"(hi));
  return r;
}

__global__ __launch_bounds__(256, 2) void cvar_mlp_kernel(
    const float* __restrict__ states, const float* __restrict__ W1,
    const float* __restrict__ b1, const float* __restrict__ W2,
    const float* __restrict__ b2, float* __restrict__ out)
{
  // double-buffered 64x256 bf16 states tile, row stride 512B, XOR-swizzled
  __shared__ __align__(16) char lds[2][BM * 512];
  __shared__ float red[2][4][BM];

  const int tid  = threadIdx.x;
  const int wid  = tid >> 6;
  const int lane = tid & 63;
  const int l15  = lane & 15;
  const int lg   = lane >> 4;          // 0..3

  // XCD-grouped: blocks with same (bidx&7) share a t-range -> W1[t] L2-local
  const int bidx = blockIdx.x;         // 0..511
  const int xcd  = bidx & 7;
  const int slot = bidx >> 3;          // 0..63
  const int t    = xcd * 4 + (slot >> 4);
  const int cg   = slot & 15;
  const int b0   = cg * (BM * NCH);

  const float*  Ag  = states + ((size_t)t * B_DIM + b0) * S_DIM;
  const float4* A4  = reinterpret_cast<const float4*>(Ag);
  const float*  W1g = W1 + (size_t)t * (S_DIM * H_DIM);

  // ---- issue chunk-0 states loads (HBM, longest latency) ----
  float4 av[16];
#pragma unroll
  for (int i = 0; i < 16; ++i)
    av[i] = A4[i * 256 + tid];

  // ---- W1 fragment preload into registers (once per block, amortized 8x) ----
  // B-frag for mfma_f32_16x16x32_bf16: lane holds col n=lane&15, k=ks*32+lg*8+j
  bf16x8 bfr[2][8];
#pragma unroll
  for (int nloc = 0; nloc < 2; ++nloc) {
    const int ncol = (wid * 2 + nloc) * 16 + l15;
#pragma unroll
    for (int ks = 0; ks < 8; ++ks) {
      const int kbase = ks * 32 + lg * 8;
      float e[8];
#pragma unroll
      for (int j = 0; j < 8; ++j)
        e[j] = W1g[(size_t)(kbase + j) * H_DIM + ncol];
      union { uint32_t u[4]; bf16x8 v; } uu;
      uu.u[0] = cvt_pk_bf16(e[0], e[1]);
      uu.u[1] = cvt_pk_bf16(e[2], e[3]);
      uu.u[2] = cvt_pk_bf16(e[4], e[5]);
      uu.u[3] = cvt_pk_bf16(e[6], e[7]);
      bfr[nloc][ks] = uu.v;
    }
  }

  float b1c[2], w2c[2];
#pragma unroll
  for (int nloc = 0; nloc < 2; ++nloc) {
    const int col = (wid * 2 + nloc) * 16 + l15;
    b1c[nloc] = b1[(size_t)t * H_DIM + col];
    w2c[nloc] = W2[(size_t)t * H_DIM + col];
  }
  const float b2t = b2[t];
  float* outt = out + (size_t)t * B_DIM + b0;

  // ---- convert chunk 0 -> lds[0] ----
#pragma unroll
  for (int i = 0; i < 16; ++i) {
    const int f   = i * 256 + tid;
    const int row = f >> 6;
    const int kq  = f & 63;
    const uint32_t lo = cvt_pk_bf16(av[i].x, av[i].y);
    const uint32_t hi = cvt_pk_bf16(av[i].z, av[i].w);
    int byteoff = row * 512 + kq * 8;
    byteoff ^= (row & 7) << 4;
    *reinterpret_cast<uint2*>(&lds[0][byteoff]) = make_uint2(lo, hi);
  }
  __syncthreads();

  // ---- pipelined chunk loop ----
  for (int c = 0; c < NCH; ++c) {
    const int cur = c & 1;

    // prefetch next chunk's states into registers (in flight across MFMA)
    if (c + 1 < NCH) {
#pragma unroll
      for (int i = 0; i < 16; ++i)
        av[i] = A4[(c + 1) * (BM * S_DIM / 4) + i * 256 + tid];
    }

    // MFMA: 64 rows x this wave's 32 cols
    f32x4 acc[4][2];
#pragma unroll
    for (int mt = 0; mt < 4; ++mt)
#pragma unroll
      for (int nloc = 0; nloc < 2; ++nloc)
        acc[mt][nloc] = (f32x4){0.f, 0.f, 0.f, 0.f};

#pragma unroll
    for (int mt = 0; mt < 4; ++mt) {
      const int row = mt * 16 + l15;
      bf16x8 afr[8];
#pragma unroll
      for (int ks = 0; ks < 8; ++ks) {
        int byteoff = row * 512 + ks * 64 + lg * 16;
        byteoff ^= (row & 7) << 4;
        afr[ks] = *reinterpret_cast<const bf16x8*>(&lds[cur][byteoff]);
      }
#pragma unroll
      for (int ks = 0; ks < 8; ++ks) {
        acc[mt][0] = __builtin_amdgcn_mfma_f32_16x16x32_bf16(afr[ks], bfr[0][ks], acc[mt][0], 0, 0, 0);
        acc[mt][1] = __builtin_amdgcn_mfma_f32_16x16x32_bf16(afr[ks], bfr[1][ks], acc[mt][1], 0, 0, 0);
      }
    }

    // fused epilogue: +b1, SiLU, *W2, 16-lane row-reduce -> red[cur]
#pragma unroll
    for (int mt = 0; mt < 4; ++mt) {
      float part[4];
#pragma unroll
      for (int r = 0; r < 4; ++r) {
        float s = 0.f;
#pragma unroll
        for (int nloc = 0; nloc < 2; ++nloc) {
          const float h   = acc[mt][nloc][r] + b1c[nloc];
          const float sig = 1.f / (1.f + __expf(-h));
          s += h * sig * w2c[nloc];
        }
        s += __shfl_xor(s, 1);
        s += __shfl_xor(s, 2);
        s += __shfl_xor(s, 4);
        s += __shfl_xor(s, 8);
        part[r] = s;
      }
      if (l15 == 0) {
#pragma unroll
        for (int r = 0; r < 4; ++r)
          red[cur][wid][mt * 16 + lg * 4 + r] = part[r];
      }
    }

    // convert prefetched chunk -> other LDS buffer (prev reads done: barrier c-1)
    if (c + 1 < NCH) {
#pragma unroll
      for (int i = 0; i < 16; ++i) {
        const int f   = i * 256 + tid;
        const int row = f >> 6;
        const int kq  = f & 63;
        const uint32_t lo = cvt_pk_bf16(av[i].x, av[i].y);
        const uint32_t hi = cvt_pk_bf16(av[i].z, av[i].w);
        int byteoff = row * 512 + kq * 8;
        byteoff ^= (row & 7) << 4;
        *reinterpret_cast<uint2*>(&lds[cur ^ 1][byteoff]) = make_uint2(lo, hi);
      }
    }
    __syncthreads();

    // cross-wave reduce + b2, write out (red[cur] reused only at c+2: safe)
    if (tid < BM) {
      const float o = red[cur][0][tid] + red[cur][1][tid] +
                      red[cur][2][tid] + red[cur][3][tid] + b2t;
      outt[c * BM + tid] = o;
    }
  }
}

extern "C" void kernel_launch(void* const* d_in, const int* in_sizes, int n_in,
                              void* d_out, int out_size, void* d_ws, size_t ws_size,
                              hipStream_t stream) {
  const float* states = (const float*)d_in[0];
  const float* W1     = (const float*)d_in[1];
  const float* b1     = (const float*)d_in[2];
  const float* W2     = (const float*)d_in[3];
  const float* b2     = (const float*)d_in[4];
  float* out          = (float*)d_out;

  const int grid = T_DIM * BLOCKS_PER_T;   // 512
  cvar_mlp_kernel<<<grid, 256, 0, stream>>>(states, W1, b1, W2, b2, out);
}